// Round 7
// baseline (671.271 us; speedup 1.0000x reference)
//
#include <hip/hip_runtime.h>
#include <math.h>

#define NN 50000
#define NE 800000
#define CH 128
#define NG 64
#define BN_EPS 1e-5f
#define POOL_CHUNK 64
#define SCAN_B 256
#define NBLK ((NN + SCAN_B - 1) / SCAN_B)   // 196
#define BKT_SHIFT 9
#define NBKT ((NN + 511) >> 9)              // 98 buckets of 512 nodes
#define PTILE 2048

typedef short bfrag8 __attribute__((ext_vector_type(8)));   // 8 bf16 (4 VGPRs)
typedef float facc4 __attribute__((ext_vector_type(4)));    // 4 fp32 acc

__device__ __forceinline__ float gelu_f(float x) {
    return 0.5f * x * (1.0f + erff(x * 0.70710678118654752440f));
}

// bf16 helpers (RNE pack, bit-exact unpack)
__device__ __forceinline__ unsigned int f2bf(float f) {
    unsigned int u = __float_as_uint(f);
    return (u + 0x7FFFu + ((u >> 16) & 1u)) >> 16;
}
__device__ __forceinline__ unsigned int pack_bf2(float lo, float hi) {
    return (f2bf(hi) << 16) | f2bf(lo);
}
__device__ __forceinline__ float bf_lo(unsigned int v) { return __uint_as_float(v << 16); }
__device__ __forceinline__ float bf_hi(unsigned int v) { return __uint_as_float(v & 0xFFFF0000u); }

// ---------------- degree histogram (node + bucket, LDS-staged buckets) ----------------
__global__ __launch_bounds__(256) void hist_k(const int* __restrict__ ei,
                                              int* __restrict__ cnt,
                                              int* __restrict__ bcnt) {
    __shared__ int bh[NBKT];
    int t = threadIdx.x;
    if (t < NBKT) bh[t] = 0;
    __syncthreads();
    int e = blockIdx.x * 256 + t;
    if (e < NE) {
        int d = ei[NE + e];
        atomicAdd(&cnt[d], 1);
        atomicAdd(&bh[d >> BKT_SHIFT], 1);
    }
    __syncthreads();
    if (t < NBKT && bh[t]) atomicAdd(&bcnt[t], bh[t]);
}

// ---------------- two-level node scan ----------------
__global__ __launch_bounds__(256) void blk_sum_k(const int* __restrict__ cnt, int* __restrict__ bsum) {
    __shared__ int sh[256];
    int i = blockIdx.x * 256 + threadIdx.x;
    sh[threadIdx.x] = (i < NN) ? cnt[i] : 0;
    __syncthreads();
    for (int off = 128; off > 0; off >>= 1) {
        if (threadIdx.x < off) sh[threadIdx.x] += sh[threadIdx.x + off];
        __syncthreads();
    }
    if (threadIdx.x == 0) bsum[blockIdx.x] = sh[0];
}

__global__ __launch_bounds__(256) void blk_scan_k(const int* __restrict__ bsum,
                                                  int* __restrict__ boffn,
                                                  int* __restrict__ row_ptr) {
    __shared__ int sh[256];
    int t = threadIdx.x;
    int v = (t < NBLK) ? bsum[t] : 0;
    sh[t] = v;
    __syncthreads();
    for (int off = 1; off < 256; off <<= 1) {
        int a = (t >= off) ? sh[t - off] : 0;
        __syncthreads();
        sh[t] += a;
        __syncthreads();
    }
    if (t < NBLK) boffn[t] = sh[t] - v;
    if (t == 255) row_ptr[NN] = sh[255];
}

// emit row_ptr + dinv (fused)
__global__ __launch_bounds__(256) void emit_k(const int* __restrict__ cnt,
                                              const int* __restrict__ boffn,
                                              int* __restrict__ row_ptr,
                                              float* __restrict__ dinv) {
    __shared__ int sh[256];
    int i = blockIdx.x * 256 + threadIdx.x;
    int t = threadIdx.x;
    int v = (i < NN) ? cnt[i] : 0;
    sh[t] = v;
    __syncthreads();
    for (int off = 1; off < 256; off <<= 1) {
        int a = (t >= off) ? sh[t - off] : 0;
        __syncthreads();
        sh[t] += a;
        __syncthreads();
    }
    if (i < NN) {
        row_ptr[i] = boffn[blockIdx.x] + sh[t] - v;
        dinv[i] = rsqrtf((float)v + 1.0f);   // +1 = self loop
    }
}

// ---------------- bucket scan (tiny) ----------------
__global__ __launch_bounds__(128) void bkt_scan_k(const int* __restrict__ bcnt,
                                                  int* __restrict__ boff,
                                                  int* __restrict__ btail) {
    __shared__ int sh[128];
    int t = threadIdx.x;
    int v = (t < NBKT) ? bcnt[t] : 0;
    sh[t] = v;
    __syncthreads();
    for (int off = 1; off < 128; off <<= 1) {
        int a = (t >= off) ? sh[t - off] : 0;
        __syncthreads();
        sh[t] += a;
        __syncthreads();
    }
    if (t < NBKT) {
        boff[t + 1] = sh[t];
        btail[t] = sh[t] - v;   // exclusive
    }
    if (t == 0) boff[0] = 0;
}

// ---------------- pass A: partition edges by dst bucket ----------------
__global__ __launch_bounds__(256) void part_k(const int* __restrict__ ei,
                                              int* __restrict__ btail,
                                              unsigned long long* __restrict__ part) {
    __shared__ int lh[NBKT];
    __shared__ int gbase[NBKT];
    int t = threadIdx.x;
    int base = blockIdx.x * PTILE;
    if (t < NBKT) lh[t] = 0;
    __syncthreads();
    int s[8], d[8], rk[8];
    #pragma unroll
    for (int i = 0; i < 8; ++i) {
        int e = base + i * 256 + t;
        if (e < NE) {
            s[i] = ei[e];
            d[i] = ei[NE + e];
            rk[i] = atomicAdd(&lh[d[i] >> BKT_SHIFT], 1);
        }
    }
    __syncthreads();
    if (t < NBKT && lh[t]) gbase[t] = atomicAdd(&btail[t], lh[t]);
    __syncthreads();
    #pragma unroll
    for (int i = 0; i < 8; ++i) {
        int e = base + i * 256 + t;
        if (e < NE) {
            int b = d[i] >> BKT_SHIFT;
            part[gbase[b] + rk[i]] =
                ((unsigned long long)(unsigned int)d[i] << 32) | (unsigned int)s[i];
        }
    }
}

// ---------------- pass B: per-bucket scatter into CSR (LDS fill, L2-local writes) ----------------
__global__ __launch_bounds__(256) void cscat_k(const unsigned long long* __restrict__ part,
                                               const int* __restrict__ boff,
                                               const int* __restrict__ row_ptr,
                                               int* __restrict__ csr_src) {
    __shared__ int fill[512];
    int b = blockIdx.x;
    int n0 = b << BKT_SHIFT;
    for (int i = threadIdx.x; i < 512; i += 256) fill[i] = 0;
    __syncthreads();
    int e0 = boff[b], e1 = boff[b + 1];
    for (int e = e0 + threadIdx.x; e < e1; e += 256) {
        unsigned long long p = part[e];
        int s = (int)(unsigned int)p;
        int d = (int)(p >> 32);
        int pos = row_ptr[d] + atomicAdd(&fill[d - n0], 1);
        csr_src[pos] = s;
    }
}

// ---------------- W -> bf16 B-fragment-order pack ----------------
__global__ __launch_bounds__(256) void wconv_k(const float* __restrict__ W,
                                               unsigned short* __restrict__ wf) {
    int u = blockIdx.x * 256 + threadIdx.x;   // 0..2047
    int nt = u >> 8, kc = (u >> 6) & 3, l = u & 63;
    int kbase = kc * 32 + (l >> 4) * 8;
    int n = nt * 16 + (l & 15);
    unsigned int p[4];
    #pragma unroll
    for (int jj = 0; jj < 4; ++jj) {
        float a = W[(kbase + 2 * jj) * 128 + n];
        float b = W[(kbase + 2 * jj + 1) * 128 + n];
        p[jj] = pack_bf2(a, b);
    }
    uint4* dst = (uint4*)(wf + (size_t)u * 8);
    *dst = make_uint4(p[0], p[1], p[2], p[3]);
}

// ---------------- MFMA GEMM: out16[N,128](bf16) = act(A[N,128]) @ W[128,128] ----------------
__global__ __launch_bounds__(256) void gemm_k(const float* __restrict__ A,
                                              const unsigned short* __restrict__ wfrag,
                                              const float* __restrict__ ss,
                                              unsigned short* __restrict__ out16) {
    __shared__ unsigned short Alds[8192];    // 64 rows x 128 k, A-fragment order
    __shared__ unsigned short Wlds[16384];   // 128x128, B-fragment order

    const int tid = threadIdx.x;
    const int row0 = blockIdx.x * 64;

    #pragma unroll
    for (int i = 0; i < 4; ++i) {
        int linear = tid + i * 256;          // 0..1023
        int r = linear >> 4;                 // row 0..63
        int g = linear & 15;                 // k-group (8 k's)
        float4 v0 = make_float4(0.f, 0.f, 0.f, 0.f);
        float4 v1 = make_float4(0.f, 0.f, 0.f, 0.f);
        if (row0 + r < NN) {
            const float4* src = (const float4*)&A[(size_t)(row0 + r) * 128 + g * 8];
            v0 = src[0];
            v1 = src[1];
            if (ss) {
                float4 sc0 = ((const float4*)ss)[g * 2];
                float4 sh0 = ((const float4*)ss)[32 + g * 2];
                float4 sc1 = ((const float4*)ss)[g * 2 + 1];
                float4 sh1 = ((const float4*)ss)[32 + g * 2 + 1];
                v0.x = gelu_f(v0.x * sc0.x + sh0.x); v0.y = gelu_f(v0.y * sc0.y + sh0.y);
                v0.z = gelu_f(v0.z * sc0.z + sh0.z); v0.w = gelu_f(v0.w * sc0.w + sh0.w);
                v1.x = gelu_f(v1.x * sc1.x + sh1.x); v1.y = gelu_f(v1.y * sc1.y + sh1.y);
                v1.z = gelu_f(v1.z * sc1.z + sh1.z); v1.w = gelu_f(v1.w * sc1.w + sh1.w);
            }
        }
        int unit = (((r >> 4) * 4 + (g >> 2)) * 64) + ((g & 3) * 16) + (r & 15);
        uint4* dst = (uint4*)(Alds + (size_t)unit * 8);
        *dst = make_uint4(pack_bf2(v0.x, v0.y), pack_bf2(v0.z, v0.w),
                          pack_bf2(v1.x, v1.y), pack_bf2(v1.z, v1.w));
    }
    #pragma unroll
    for (int i = 0; i < 8; ++i) {
        int linear = tid + i * 256;
        ((uint4*)Wlds)[linear] = ((const uint4*)wfrag)[linear];
    }
    __syncthreads();

    const int w = tid >> 6;
    const int l = tid & 63;
    const int quad = l >> 4;
    const int m = l & 15;

    facc4 acc[8];
    #pragma unroll
    for (int nt = 0; nt < 8; ++nt) acc[nt] = (facc4){0.f, 0.f, 0.f, 0.f};

    #pragma unroll
    for (int kc = 0; kc < 4; ++kc) {
        bfrag8 a = *((const bfrag8*)(Alds + ((size_t)((w * 4 + kc) * 64 + l)) * 8));
        #pragma unroll
        for (int nt = 0; nt < 8; ++nt) {
            bfrag8 b = *((const bfrag8*)(Wlds + ((size_t)((nt * 4 + kc) * 64 + l)) * 8));
            acc[nt] = __builtin_amdgcn_mfma_f32_16x16x32_bf16(a, b, acc[nt], 0, 0, 0);
        }
    }

    #pragma unroll
    for (int nt = 0; nt < 8; ++nt) {
        #pragma unroll
        for (int r = 0; r < 4; ++r) {
            int row = row0 + w * 16 + quad * 4 + r;
            if (row < NN) out16[(size_t)row * 128 + nt * 16 + m] = (unsigned short)f2bf(acc[nt][r]);
        }
    }
}

// ---------------- CSR aggregation: one wave per node, 8-deep bf16 gather ----------------
__global__ __launch_bounds__(256) void csr_agg_k(const int* __restrict__ row_ptr,
                                                 const int* __restrict__ csr_src,
                                                 const unsigned int* __restrict__ hw16,
                                                 const float* __restrict__ bias,
                                                 const float* __restrict__ dinv,
                                                 float* __restrict__ out) {
    int node = (blockIdx.x * 256 + threadIdx.x) >> 6;
    if (node >= NN) return;
    int lane = threadIdx.x & 63;

    float di = dinv[node];
    float sw = di * di;
    float2 b = ((const float2*)bias)[lane];
    unsigned int hs = hw16[(size_t)node * 64 + lane];
    float selfx = b.x + bf_lo(hs) * sw;
    float selfy = b.y + bf_hi(hs) * sw;

    float a0x = 0.f, a0y = 0.f, a1x = 0.f, a1y = 0.f;
    float a2x = 0.f, a2y = 0.f, a3x = 0.f, a3y = 0.f;

    int j = row_ptr[node];
    int j1 = row_ptr[node + 1];
    for (; j + 7 < j1; j += 8) {
        int s[8];
        #pragma unroll
        for (int k = 0; k < 8; ++k) s[k] = csr_src[j + k];
        float w[8];
        #pragma unroll
        for (int k = 0; k < 8; ++k) w[k] = dinv[s[k]];
        unsigned int v[8];
        #pragma unroll
        for (int k = 0; k < 8; ++k) v[k] = hw16[(size_t)s[k] * 64 + lane];
        a0x += bf_lo(v[0]) * w[0] + bf_lo(v[1]) * w[1];
        a0y += bf_hi(v[0]) * w[0] + bf_hi(v[1]) * w[1];
        a1x += bf_lo(v[2]) * w[2] + bf_lo(v[3]) * w[3];
        a1y += bf_hi(v[2]) * w[2] + bf_hi(v[3]) * w[3];
        a2x += bf_lo(v[4]) * w[4] + bf_lo(v[5]) * w[5];
        a2y += bf_hi(v[4]) * w[4] + bf_hi(v[5]) * w[5];
        a3x += bf_lo(v[6]) * w[6] + bf_lo(v[7]) * w[7];
        a3y += bf_hi(v[6]) * w[6] + bf_hi(v[7]) * w[7];
    }
    for (; j + 1 < j1; j += 2) {
        int s0 = csr_src[j], s1 = csr_src[j + 1];
        float w0 = dinv[s0], w1 = dinv[s1];
        unsigned int v0 = hw16[(size_t)s0 * 64 + lane];
        unsigned int v1 = hw16[(size_t)s1 * 64 + lane];
        a0x += bf_lo(v0) * w0 + bf_lo(v1) * w1;
        a0y += bf_hi(v0) * w0 + bf_hi(v1) * w1;
    }
    if (j < j1) {
        int s = csr_src[j];
        float w = dinv[s];
        unsigned int v = hw16[(size_t)s * 64 + lane];
        a0x += bf_lo(v) * w;
        a0y += bf_hi(v) * w;
    }
    float ox = selfx + di * ((a0x + a1x) + (a2x + a3x));
    float oy = selfy + di * ((a0y + a1y) + (a2y + a3y));
    ((float2*)out)[(size_t)node * 64 + lane] = make_float2(ox, oy);
}

// ---------------- batchnorm stats ----------------
__global__ __launch_bounds__(256) void bn_stats_k(const float* __restrict__ h, float* __restrict__ sums) {
    int c = threadIdx.x & 127;
    int half = threadIdx.x >> 7;
    int r0 = blockIdx.x * 128 + half;
    float s = 0.f, ss = 0.f;
    #pragma unroll 4
    for (int i = 0; i < 64; ++i) {
        int r = r0 + i * 2;
        if (r < NN) {
            float v = h[(size_t)r * 128 + c];
            s += v; ss += v * v;
        }
    }
    __shared__ float sh_s[128], sh_ss[128];
    if (half == 1) { sh_s[c] = s; sh_ss[c] = ss; }
    __syncthreads();
    if (half == 0) {
        atomicAdd(&sums[c], s + sh_s[c]);
        atomicAdd(&sums[128 + c], ss + sh_ss[c]);
    }
}

__global__ __launch_bounds__(128) void bn_finalize_k(const float* __restrict__ sums,
                                                     const float* __restrict__ g,
                                                     const float* __restrict__ beta,
                                                     float* __restrict__ ss) {
    int c = threadIdx.x;
    float mean = sums[c] * (1.0f / NN);
    float var = sums[128 + c] * (1.0f / NN) - mean * mean;
    float sc = g[c] * rsqrtf(var + BN_EPS);
    ss[c] = sc;
    ss[128 + c] = beta[c] - mean * sc;
}

// ---------------- global mean pool: chunked sum + finalize ----------------
__global__ __launch_bounds__(128) void pool_sum_k(const float* __restrict__ h,
                                                  const int* __restrict__ batch,
                                                  float* __restrict__ sums) {
    int r0 = blockIdx.x * POOL_CHUNK;
    int r1 = min(r0 + POOL_CHUNK, NN);
    if (r0 >= NN) return;
    int c = threadIdx.x;
    float acc = 0.f;
    int g = batch[r0];
    for (int r = r0; r < r1; ++r) {
        int gr = batch[r];
        if (gr != g) {
            atomicAdd(&sums[g * 128 + c], acc);
            acc = 0.f;
            g = gr;
        }
        acc += h[(size_t)r * 128 + c];
    }
    atomicAdd(&sums[g * 128 + c], acc);
}

__device__ __forceinline__ int lower_bound_dev(const int* __restrict__ a, int n, int key) {
    int lo = 0, hi = n;
    while (lo < hi) {
        int mid = (lo + hi) >> 1;
        if (a[mid] < key) lo = mid + 1; else hi = mid;
    }
    return lo;
}

__global__ __launch_bounds__(128) void pool_div_k(const float* __restrict__ sums,
                                                  const int* __restrict__ batch,
                                                  float* __restrict__ pooled) {
    int g = blockIdx.x;
    int a = lower_bound_dev(batch, NN, g);
    int b = lower_bound_dev(batch, NN, g + 1);
    float inv = 1.0f / fmaxf((float)(b - a), 1.0f);
    int c = threadIdx.x;
    pooled[g * 128 + c] = sums[g * 128 + c] * inv;
}

// ---------------- MLP head ----------------
__global__ __launch_bounds__(128) void head_k(const float* __restrict__ pooled,
                                              const float* __restrict__ W0, const float* __restrict__ b0,
                                              const float* __restrict__ W1, const float* __restrict__ b1,
                                              const float* __restrict__ W2, const float* __restrict__ b2,
                                              float* __restrict__ out) {
    __shared__ float r0[128], r1[128];
    int g = blockIdx.x, t = threadIdx.x;
    r0[t] = pooled[g * 128 + t];
    __syncthreads();
    float acc = b0[t];
    for (int k = 0; k < 128; ++k) acc += r0[k] * W0[k * 128 + t];
    r1[t] = gelu_f(acc);
    __syncthreads();
    acc = b1[t];
    for (int k = 0; k < 128; ++k) acc += r1[k] * W1[k * 128 + t];
    float y = gelu_f(acc);
    __syncthreads();
    r0[t] = y;
    __syncthreads();
    if (t < 10) {
        acc = b2[t];
        for (int k = 0; k < 128; ++k) acc += r0[k] * W2[k * 10 + t];
        out[g * 10 + t] = acc;
    }
}

extern "C" void kernel_launch(void* const* d_in, const int* in_sizes, int n_in,
                              void* d_out, int out_size, void* d_ws, size_t ws_size,
                              hipStream_t stream) {
    const float* x      = (const float*)d_in[0];
    const int*   ei     = (const int*)d_in[1];
    const int*   batch  = (const int*)d_in[2];
    const float* Wb0    = (const float*)d_in[4];
    const float* bb0    = (const float*)d_in[5];
    const float* gb0    = (const float*)d_in[6];
    const float* betab0 = (const float*)d_in[7];
    const float* Wb1    = (const float*)d_in[8];
    const float* bb1    = (const float*)d_in[9];
    const float* Wa0    = (const float*)d_in[10];
    const float* ba0    = (const float*)d_in[11];
    const float* ga0    = (const float*)d_in[12];
    const float* bea0   = (const float*)d_in[13];
    const float* Wa1    = (const float*)d_in[14];
    const float* ba1    = (const float*)d_in[15];
    const float* ga1    = (const float*)d_in[16];
    const float* bea1   = (const float*)d_in[17];
    const float* Wa2    = (const float*)d_in[18];
    const float* ba2    = (const float*)d_in[19];
    const float* Wh0    = (const float*)d_in[20];
    const float* bh0    = (const float*)d_in[21];
    const float* Wh1    = (const float*)d_in[22];
    const float* bh1    = (const float*)d_in[23];
    const float* Wh2    = (const float*)d_in[24];
    const float* bh2    = (const float*)d_in[25];
    float* out = (float*)d_out;

    char* ws = (char*)d_ws;
    unsigned int* hw16 = (unsigned int*)ws;            ws += (size_t)NN * 64 * 4;   // bf16 GEMM out
    float* bufB    = (float*)ws;                       ws += (size_t)NN * CH * 4;
    float* bufC    = (float*)ws;                       ws += (size_t)NN * CH * 4;
    int*   cnt     = (int*)ws;                         ws += (size_t)NN * 4;
    int*   bcnt    = (int*)ws;                         ws += 128 * 4;               // zeroed with cnt
    float* dinv    = (float*)ws;                       ws += (size_t)NN * 4;
    int*   row_ptr = (int*)ws;                         ws += (size_t)(NN + 1) * 4;
    int*   csr_src = (int*)ws;                         ws += (size_t)NE * 4;
    unsigned long long* part = (unsigned long long*)ws; ws += (size_t)NE * 8;
    unsigned short* wf = (unsigned short*)ws;          ws += (size_t)5 * 16384 * 2;
    int*   bsum    = (int*)ws;                         ws += 256 * 4;
    int*   boffn   = (int*)ws;                         ws += 256 * 4;
    int*   boff    = (int*)ws;                         ws += 256 * 4;
    int*   btail   = (int*)ws;                         ws += 256 * 4;
    float* bnss    = (float*)ws;                       ws += 256 * 4;
    float* ssbuf   = (float*)ws;                       ws += 256 * 4;
    float* psum    = (float*)ws;                       ws += (size_t)NG * CH * 4;
    float* pooled  = (float*)ws;                       ws += (size_t)NG * CH * 4;

    unsigned short* wfb0 = wf;
    unsigned short* wfb1 = wf + 16384;
    unsigned short* wfa0 = wf + 2 * 16384;
    unsigned short* wfa1 = wf + 3 * 16384;
    unsigned short* wfa2 = wf + 4 * 16384;

    // W packing (independent of CSR build)
    wconv_k<<<8, 256, 0, stream>>>(Wb0, wfb0);
    wconv_k<<<8, 256, 0, stream>>>(Wb1, wfb1);
    wconv_k<<<8, 256, 0, stream>>>(Wa0, wfa0);
    wconv_k<<<8, 256, 0, stream>>>(Wa1, wfa1);
    wconv_k<<<8, 256, 0, stream>>>(Wa2, wfa2);

    // CSR build (bucketed two-pass scatter)
    hipMemsetAsync(cnt, 0, (NN + 128) * sizeof(int), stream);   // cnt + bcnt
    hist_k<<<(NE + 255) / 256, 256, 0, stream>>>(ei, cnt, bcnt);
    blk_sum_k<<<NBLK, 256, 0, stream>>>(cnt, bsum);
    blk_scan_k<<<1, 256, 0, stream>>>(bsum, boffn, row_ptr);
    emit_k<<<NBLK, 256, 0, stream>>>(cnt, boffn, row_ptr, dinv);
    bkt_scan_k<<<1, 128, 0, stream>>>(bcnt, boff, btail);
    part_k<<<(NE + PTILE - 1) / PTILE, 256, 0, stream>>>(ei, btail, part);
    cscat_k<<<NBKT, 256, 0, stream>>>(part, boff, row_ptr, csr_src);

    auto conv = [&](const float* in, const unsigned short* wfrag, const float* b,
                    const float* ss, float* o) {
        gemm_k<<<(NN + 63) / 64, 256, 0, stream>>>(in, wfrag, ss, (unsigned short*)hw16);
        csr_agg_k<<<(NN * 64 + 255) / 256, 256, 0, stream>>>(row_ptr, csr_src, hw16, b, dinv, o);
    };
    auto bn_stats = [&](const float* h, const float* g, const float* beta) {
        hipMemsetAsync(bnss, 0, 256 * sizeof(float), stream);
        bn_stats_k<<<(NN + 127) / 128, 256, 0, stream>>>(h, bnss);
        bn_finalize_k<<<1, 128, 0, stream>>>(bnss, g, beta, ssbuf);
    };

    conv(x, wfb0, bb0, nullptr, bufB);           // conv b0
    bn_stats(bufB, gb0, betab0);
    conv(bufB, wfb1, bb1, ssbuf, bufC);          // conv b1 (A-load: gelu(bn(h)))
    conv(bufC, wfa0, ba0, nullptr, bufB);        // conv a0
    bn_stats(bufB, ga0, bea0);
    conv(bufB, wfa1, ba1, ssbuf, bufC);          // conv a1
    bn_stats(bufC, ga1, bea1);
    conv(bufC, wfa2, ba2, ssbuf, bufB);          // conv a2

    hipMemsetAsync(psum, 0, NG * CH * sizeof(float), stream);
    pool_sum_k<<<(NN + POOL_CHUNK - 1) / POOL_CHUNK, 128, 0, stream>>>(bufB, batch, psum);
    pool_div_k<<<NG, 128, 0, stream>>>(psum, batch, pooled);
    head_k<<<NG, 128, 0, stream>>>(pooled, Wh0, bh0, Wh1, bh1, Wh2, bh2, out);
}

// Round 8
// 595.373 us; speedup vs baseline: 1.1275x; 1.1275x over previous
//
#include <hip/hip_runtime.h>
#include <math.h>

#define NN 50000
#define NE 800000
#define CH 128
#define NG 64
#define BN_EPS 1e-5f
#define POOL_CHUNK 64
#define BKT_SHIFT 9
#define NBKT ((NN + 511) >> 9)              // 98 buckets of 512 nodes
#define PTILE 2048

typedef short bfrag8 __attribute__((ext_vector_type(8)));   // 8 bf16 (4 VGPRs)
typedef float facc4 __attribute__((ext_vector_type(4)));    // 4 fp32 acc

__device__ __forceinline__ float gelu_f(float x) {
    return 0.5f * x * (1.0f + erff(x * 0.70710678118654752440f));
}

// bf16 helpers (RNE pack, bit-exact unpack)
__device__ __forceinline__ unsigned int f2bf(float f) {
    unsigned int u = __float_as_uint(f);
    return (u + 0x7FFFu + ((u >> 16) & 1u)) >> 16;
}
__device__ __forceinline__ unsigned int pack_bf2(float lo, float hi) {
    return (f2bf(hi) << 16) | f2bf(lo);
}
__device__ __forceinline__ float bf_lo(unsigned int v) { return __uint_as_float(v << 16); }
__device__ __forceinline__ float bf_hi(unsigned int v) { return __uint_as_float(v & 0xFFFF0000u); }

// ---------------- bucket histogram (98 counters, 2048 edges/block) ----------------
__global__ __launch_bounds__(256) void bhist_k(const int* __restrict__ ei, int* __restrict__ bcnt) {
    __shared__ int lh[NBKT];
    int t = threadIdx.x;
    int base = blockIdx.x * PTILE;
    if (t < NBKT) lh[t] = 0;
    __syncthreads();
    #pragma unroll
    for (int i = 0; i < 8; ++i) {
        int e = base + i * 256 + t;
        if (e < NE) atomicAdd(&lh[ei[NE + e] >> BKT_SHIFT], 1);
    }
    __syncthreads();
    if (t < NBKT && lh[t]) atomicAdd(&bcnt[t], lh[t]);
}

// ---------------- bucket scan (tiny) ----------------
__global__ __launch_bounds__(128) void bkt_scan_k(const int* __restrict__ bcnt,
                                                  int* __restrict__ boff,
                                                  int* __restrict__ btail,
                                                  int* __restrict__ row_ptr) {
    __shared__ int sh[128];
    int t = threadIdx.x;
    int v = (t < NBKT) ? bcnt[t] : 0;
    sh[t] = v;
    __syncthreads();
    for (int off = 1; off < 128; off <<= 1) {
        int a = (t >= off) ? sh[t - off] : 0;
        __syncthreads();
        sh[t] += a;
        __syncthreads();
    }
    if (t < NBKT) {
        boff[t + 1] = sh[t];
        btail[t] = sh[t] - v;   // exclusive
    }
    if (t == 0) { boff[0] = 0; row_ptr[NN] = NE; }
}

// ---------------- pass A: partition edges by dst bucket ----------------
__global__ __launch_bounds__(256) void part_k(const int* __restrict__ ei,
                                              int* __restrict__ btail,
                                              unsigned long long* __restrict__ part) {
    __shared__ int lh[NBKT];
    __shared__ int gbase[NBKT];
    int t = threadIdx.x;
    int base = blockIdx.x * PTILE;
    if (t < NBKT) lh[t] = 0;
    __syncthreads();
    int s[8], d[8], rk[8];
    #pragma unroll
    for (int i = 0; i < 8; ++i) {
        int e = base + i * 256 + t;
        if (e < NE) {
            s[i] = ei[e];
            d[i] = ei[NE + e];
            rk[i] = atomicAdd(&lh[d[i] >> BKT_SHIFT], 1);
        }
    }
    __syncthreads();
    if (t < NBKT && lh[t]) gbase[t] = atomicAdd(&btail[t], lh[t]);
    __syncthreads();
    #pragma unroll
    for (int i = 0; i < 8; ++i) {
        int e = base + i * 256 + t;
        if (e < NE) {
            int b = d[i] >> BKT_SHIFT;
            part[gbase[b] + rk[i]] =
                ((unsigned long long)(unsigned int)d[i] << 32) | (unsigned int)s[i];
        }
    }
}

// ---------------- pass B: per-bucket count + scan + emit row_ptr/dinv + scatter ----------------
__global__ __launch_bounds__(256) void cscat2_k(const unsigned long long* __restrict__ part,
                                                const int* __restrict__ boff,
                                                int* __restrict__ row_ptr,
                                                float* __restrict__ dinv,
                                                int* __restrict__ csr_src) {
    __shared__ int cnt_l[512];
    __shared__ int off_l[512];
    __shared__ int psum[256];
    int b = blockIdx.x;
    int n0 = b << BKT_SHIFT;
    int t = threadIdx.x;
    cnt_l[t] = 0;
    cnt_l[t + 256] = 0;
    __syncthreads();
    int e0 = boff[b], e1 = boff[b + 1];
    // count per-node (LDS, 512 counters)
    for (int e = e0 + t; e < e1; e += 256) {
        int d = (int)(part[e] >> 32);
        atomicAdd(&cnt_l[d - n0], 1);
    }
    __syncthreads();
    // scan 512 counters with 256 threads (each owns pair 2t, 2t+1)
    int c0 = cnt_l[2 * t], c1 = cnt_l[2 * t + 1];
    psum[t] = c0 + c1;
    __syncthreads();
    for (int off = 1; off < 256; off <<= 1) {
        int a = (t >= off) ? psum[t - off] : 0;
        __syncthreads();
        psum[t] += a;
        __syncthreads();
    }
    int excl = (t == 0) ? 0 : psum[t - 1];
    off_l[2 * t] = excl;
    off_l[2 * t + 1] = excl + c0;
    // emit row_ptr + dinv for the 2 owned nodes
    int gbase = boff[b];
    #pragma unroll
    for (int k = 0; k < 2; ++k) {
        int ln = 2 * t + k;
        int n = n0 + ln;
        if (n < NN) {
            int c = (k == 0) ? c0 : c1;
            row_ptr[n] = gbase + off_l[ln];
            dinv[n] = rsqrtf((float)c + 1.0f);   // +1 = self loop
        }
    }
    __syncthreads();
    // reset fill counters, then scatter
    cnt_l[t] = 0;
    cnt_l[t + 256] = 0;
    __syncthreads();
    for (int e = e0 + t; e < e1; e += 256) {
        unsigned long long p = part[e];
        int s = (int)(unsigned int)p;
        int ld = (int)(p >> 32) - n0;
        int pos = gbase + off_l[ld] + atomicAdd(&cnt_l[ld], 1);
        csr_src[pos] = s;
    }
}

// ---------------- W -> bf16 B-fragment-order pack ----------------
__global__ __launch_bounds__(256) void wconv_k(const float* __restrict__ W,
                                               unsigned short* __restrict__ wf) {
    int u = blockIdx.x * 256 + threadIdx.x;   // 0..2047
    int nt = u >> 8, kc = (u >> 6) & 3, l = u & 63;
    int kbase = kc * 32 + (l >> 4) * 8;
    int n = nt * 16 + (l & 15);
    unsigned int p[4];
    #pragma unroll
    for (int jj = 0; jj < 4; ++jj) {
        float a = W[(kbase + 2 * jj) * 128 + n];
        float b = W[(kbase + 2 * jj + 1) * 128 + n];
        p[jj] = pack_bf2(a, b);
    }
    uint4* dst = (uint4*)(wf + (size_t)u * 8);
    *dst = make_uint4(p[0], p[1], p[2], p[3]);
}

// ---------------- MFMA GEMM: out16[N,128](bf16) = act(A[N,128]) @ W[128,128] ----------------
__global__ __launch_bounds__(256) void gemm_k(const float* __restrict__ A,
                                              const unsigned short* __restrict__ wfrag,
                                              const float* __restrict__ ss,
                                              unsigned short* __restrict__ out16) {
    __shared__ unsigned short Alds[8192];    // 64 rows x 128 k, A-fragment order
    __shared__ unsigned short Wlds[16384];   // 128x128, B-fragment order

    const int tid = threadIdx.x;
    const int row0 = blockIdx.x * 64;

    #pragma unroll
    for (int i = 0; i < 4; ++i) {
        int linear = tid + i * 256;          // 0..1023
        int r = linear >> 4;                 // row 0..63
        int g = linear & 15;                 // k-group (8 k's)
        float4 v0 = make_float4(0.f, 0.f, 0.f, 0.f);
        float4 v1 = make_float4(0.f, 0.f, 0.f, 0.f);
        if (row0 + r < NN) {
            const float4* src = (const float4*)&A[(size_t)(row0 + r) * 128 + g * 8];
            v0 = src[0];
            v1 = src[1];
            if (ss) {
                float4 sc0 = ((const float4*)ss)[g * 2];
                float4 sh0 = ((const float4*)ss)[32 + g * 2];
                float4 sc1 = ((const float4*)ss)[g * 2 + 1];
                float4 sh1 = ((const float4*)ss)[32 + g * 2 + 1];
                v0.x = gelu_f(v0.x * sc0.x + sh0.x); v0.y = gelu_f(v0.y * sc0.y + sh0.y);
                v0.z = gelu_f(v0.z * sc0.z + sh0.z); v0.w = gelu_f(v0.w * sc0.w + sh0.w);
                v1.x = gelu_f(v1.x * sc1.x + sh1.x); v1.y = gelu_f(v1.y * sc1.y + sh1.y);
                v1.z = gelu_f(v1.z * sc1.z + sh1.z); v1.w = gelu_f(v1.w * sc1.w + sh1.w);
            }
        }
        int unit = (((r >> 4) * 4 + (g >> 2)) * 64) + ((g & 3) * 16) + (r & 15);
        uint4* dst = (uint4*)(Alds + (size_t)unit * 8);
        *dst = make_uint4(pack_bf2(v0.x, v0.y), pack_bf2(v0.z, v0.w),
                          pack_bf2(v1.x, v1.y), pack_bf2(v1.z, v1.w));
    }
    #pragma unroll
    for (int i = 0; i < 8; ++i) {
        int linear = tid + i * 256;
        ((uint4*)Wlds)[linear] = ((const uint4*)wfrag)[linear];
    }
    __syncthreads();

    const int w = tid >> 6;
    const int l = tid & 63;
    const int quad = l >> 4;
    const int m = l & 15;

    facc4 acc[8];
    #pragma unroll
    for (int nt = 0; nt < 8; ++nt) acc[nt] = (facc4){0.f, 0.f, 0.f, 0.f};

    #pragma unroll
    for (int kc = 0; kc < 4; ++kc) {
        bfrag8 a = *((const bfrag8*)(Alds + ((size_t)((w * 4 + kc) * 64 + l)) * 8));
        #pragma unroll
        for (int nt = 0; nt < 8; ++nt) {
            bfrag8 b = *((const bfrag8*)(Wlds + ((size_t)((nt * 4 + kc) * 64 + l)) * 8));
            acc[nt] = __builtin_amdgcn_mfma_f32_16x16x32_bf16(a, b, acc[nt], 0, 0, 0);
        }
    }

    #pragma unroll
    for (int nt = 0; nt < 8; ++nt) {
        #pragma unroll
        for (int r = 0; r < 4; ++r) {
            int row = row0 + w * 16 + quad * 4 + r;
            if (row < NN) out16[(size_t)row * 128 + nt * 16 + m] = (unsigned short)f2bf(acc[nt][r]);
        }
    }
}

// ---------------- CSR aggregation: one wave per node, 8-deep bf16 gather ----------------
__global__ __launch_bounds__(256) void csr_agg_k(const int* __restrict__ row_ptr,
                                                 const int* __restrict__ csr_src,
                                                 const unsigned int* __restrict__ hw16,
                                                 const float* __restrict__ bias,
                                                 const float* __restrict__ dinv,
                                                 float* __restrict__ out) {
    int node = (blockIdx.x * 256 + threadIdx.x) >> 6;
    if (node >= NN) return;
    int lane = threadIdx.x & 63;

    float di = dinv[node];
    float sw = di * di;
    float2 b = ((const float2*)bias)[lane];
    unsigned int hs = hw16[(size_t)node * 64 + lane];
    float selfx = b.x + bf_lo(hs) * sw;
    float selfy = b.y + bf_hi(hs) * sw;

    float a0x = 0.f, a0y = 0.f, a1x = 0.f, a1y = 0.f;
    float a2x = 0.f, a2y = 0.f, a3x = 0.f, a3y = 0.f;

    int j = row_ptr[node];
    int j1 = row_ptr[node + 1];
    for (; j + 7 < j1; j += 8) {
        int s[8];
        #pragma unroll
        for (int k = 0; k < 8; ++k) s[k] = csr_src[j + k];
        float w[8];
        #pragma unroll
        for (int k = 0; k < 8; ++k) w[k] = dinv[s[k]];
        unsigned int v[8];
        #pragma unroll
        for (int k = 0; k < 8; ++k) v[k] = hw16[(size_t)s[k] * 64 + lane];
        a0x += bf_lo(v[0]) * w[0] + bf_lo(v[1]) * w[1];
        a0y += bf_hi(v[0]) * w[0] + bf_hi(v[1]) * w[1];
        a1x += bf_lo(v[2]) * w[2] + bf_lo(v[3]) * w[3];
        a1y += bf_hi(v[2]) * w[2] + bf_hi(v[3]) * w[3];
        a2x += bf_lo(v[4]) * w[4] + bf_lo(v[5]) * w[5];
        a2y += bf_hi(v[4]) * w[4] + bf_hi(v[5]) * w[5];
        a3x += bf_lo(v[6]) * w[6] + bf_lo(v[7]) * w[7];
        a3y += bf_hi(v[6]) * w[6] + bf_hi(v[7]) * w[7];
    }
    for (; j + 1 < j1; j += 2) {
        int s0 = csr_src[j], s1 = csr_src[j + 1];
        float w0 = dinv[s0], w1 = dinv[s1];
        unsigned int v0 = hw16[(size_t)s0 * 64 + lane];
        unsigned int v1 = hw16[(size_t)s1 * 64 + lane];
        a0x += bf_lo(v0) * w0 + bf_lo(v1) * w1;
        a0y += bf_hi(v0) * w0 + bf_hi(v1) * w1;
    }
    if (j < j1) {
        int s = csr_src[j];
        float w = dinv[s];
        unsigned int v = hw16[(size_t)s * 64 + lane];
        a0x += bf_lo(v) * w;
        a0y += bf_hi(v) * w;
    }
    float ox = selfx + di * ((a0x + a1x) + (a2x + a3x));
    float oy = selfy + di * ((a0y + a1y) + (a2y + a3y));
    ((float2*)out)[(size_t)node * 64 + lane] = make_float2(ox, oy);
}

// ---------------- batchnorm stats ----------------
__global__ __launch_bounds__(256) void bn_stats_k(const float* __restrict__ h, float* __restrict__ sums) {
    int c = threadIdx.x & 127;
    int half = threadIdx.x >> 7;
    int r0 = blockIdx.x * 128 + half;
    float s = 0.f, ss = 0.f;
    #pragma unroll 4
    for (int i = 0; i < 64; ++i) {
        int r = r0 + i * 2;
        if (r < NN) {
            float v = h[(size_t)r * 128 + c];
            s += v; ss += v * v;
        }
    }
    __shared__ float sh_s[128], sh_ss[128];
    if (half == 1) { sh_s[c] = s; sh_ss[c] = ss; }
    __syncthreads();
    if (half == 0) {
        atomicAdd(&sums[c], s + sh_s[c]);
        atomicAdd(&sums[128 + c], ss + sh_ss[c]);
    }
}

__global__ __launch_bounds__(128) void bn_finalize_k(const float* __restrict__ sums,
                                                     const float* __restrict__ g,
                                                     const float* __restrict__ beta,
                                                     float* __restrict__ ss) {
    int c = threadIdx.x;
    float mean = sums[c] * (1.0f / NN);
    float var = sums[128 + c] * (1.0f / NN) - mean * mean;
    float sc = g[c] * rsqrtf(var + BN_EPS);
    ss[c] = sc;
    ss[128 + c] = beta[c] - mean * sc;
}

// ---------------- global mean pool: chunked sum + finalize ----------------
__global__ __launch_bounds__(128) void pool_sum_k(const float* __restrict__ h,
                                                  const int* __restrict__ batch,
                                                  float* __restrict__ sums) {
    int r0 = blockIdx.x * POOL_CHUNK;
    int r1 = min(r0 + POOL_CHUNK, NN);
    if (r0 >= NN) return;
    int c = threadIdx.x;
    float acc = 0.f;
    int g = batch[r0];
    for (int r = r0; r < r1; ++r) {
        int gr = batch[r];
        if (gr != g) {
            atomicAdd(&sums[g * 128 + c], acc);
            acc = 0.f;
            g = gr;
        }
        acc += h[(size_t)r * 128 + c];
    }
    atomicAdd(&sums[g * 128 + c], acc);
}

__device__ __forceinline__ int lower_bound_dev(const int* __restrict__ a, int n, int key) {
    int lo = 0, hi = n;
    while (lo < hi) {
        int mid = (lo + hi) >> 1;
        if (a[mid] < key) lo = mid + 1; else hi = mid;
    }
    return lo;
}

__global__ __launch_bounds__(128) void pool_div_k(const float* __restrict__ sums,
                                                  const int* __restrict__ batch,
                                                  float* __restrict__ pooled) {
    int g = blockIdx.x;
    int a = lower_bound_dev(batch, NN, g);
    int b = lower_bound_dev(batch, NN, g + 1);
    float inv = 1.0f / fmaxf((float)(b - a), 1.0f);
    int c = threadIdx.x;
    pooled[g * 128 + c] = sums[g * 128 + c] * inv;
}

// ---------------- MLP head ----------------
__global__ __launch_bounds__(128) void head_k(const float* __restrict__ pooled,
                                              const float* __restrict__ W0, const float* __restrict__ b0,
                                              const float* __restrict__ W1, const float* __restrict__ b1,
                                              const float* __restrict__ W2, const float* __restrict__ b2,
                                              float* __restrict__ out) {
    __shared__ float r0[128], r1[128];
    int g = blockIdx.x, t = threadIdx.x;
    r0[t] = pooled[g * 128 + t];
    __syncthreads();
    float acc = b0[t];
    for (int k = 0; k < 128; ++k) acc += r0[k] * W0[k * 128 + t];
    r1[t] = gelu_f(acc);
    __syncthreads();
    acc = b1[t];
    for (int k = 0; k < 128; ++k) acc += r1[k] * W1[k * 128 + t];
    float y = gelu_f(acc);
    __syncthreads();
    r0[t] = y;
    __syncthreads();
    if (t < 10) {
        acc = b2[t];
        for (int k = 0; k < 128; ++k) acc += r0[k] * W2[k * 10 + t];
        out[g * 10 + t] = acc;
    }
}

extern "C" void kernel_launch(void* const* d_in, const int* in_sizes, int n_in,
                              void* d_out, int out_size, void* d_ws, size_t ws_size,
                              hipStream_t stream) {
    const float* x      = (const float*)d_in[0];
    const int*   ei     = (const int*)d_in[1];
    const int*   batch  = (const int*)d_in[2];
    const float* Wb0    = (const float*)d_in[4];
    const float* bb0    = (const float*)d_in[5];
    const float* gb0    = (const float*)d_in[6];
    const float* betab0 = (const float*)d_in[7];
    const float* Wb1    = (const float*)d_in[8];
    const float* bb1    = (const float*)d_in[9];
    const float* Wa0    = (const float*)d_in[10];
    const float* ba0    = (const float*)d_in[11];
    const float* ga0    = (const float*)d_in[12];
    const float* bea0   = (const float*)d_in[13];
    const float* Wa1    = (const float*)d_in[14];
    const float* ba1    = (const float*)d_in[15];
    const float* ga1    = (const float*)d_in[16];
    const float* bea1   = (const float*)d_in[17];
    const float* Wa2    = (const float*)d_in[18];
    const float* ba2    = (const float*)d_in[19];
    const float* Wh0    = (const float*)d_in[20];
    const float* bh0    = (const float*)d_in[21];
    const float* Wh1    = (const float*)d_in[22];
    const float* bh1    = (const float*)d_in[23];
    const float* Wh2    = (const float*)d_in[24];
    const float* bh2    = (const float*)d_in[25];
    float* out = (float*)d_out;

    char* ws = (char*)d_ws;
    unsigned int* hw16 = (unsigned int*)ws;            ws += (size_t)NN * 64 * 4;   // bf16 GEMM out
    float* bufB    = (float*)ws;                       ws += (size_t)NN * CH * 4;
    float* bufC    = (float*)ws;                       ws += (size_t)NN * CH * 4;
    float* dinv    = (float*)ws;                       ws += (size_t)NN * 4;
    int*   row_ptr = (int*)ws;                         ws += (size_t)(NN + 1) * 4;
    int*   csr_src = (int*)ws;                         ws += (size_t)NE * 4;
    unsigned long long* part = (unsigned long long*)ws; ws += (size_t)NE * 8;
    unsigned short* wf = (unsigned short*)ws;          ws += (size_t)5 * 16384 * 2;
    int*   bcnt    = (int*)ws;                         ws += 128 * 4;
    int*   boff    = (int*)ws;                         ws += 128 * 4;
    int*   btail   = (int*)ws;                         ws += 128 * 4;
    float* bnss    = (float*)ws;                       ws += 256 * 4;
    float* ssbuf   = (float*)ws;                       ws += 256 * 4;
    float* psum    = (float*)ws;                       ws += (size_t)NG * CH * 4;
    float* pooled  = (float*)ws;                       ws += (size_t)NG * CH * 4;

    unsigned short* wfb0 = wf;
    unsigned short* wfb1 = wf + 16384;
    unsigned short* wfa0 = wf + 2 * 16384;
    unsigned short* wfa1 = wf + 3 * 16384;
    unsigned short* wfa2 = wf + 4 * 16384;

    // W packing (independent of CSR build)
    wconv_k<<<8, 256, 0, stream>>>(Wb0, wfb0);
    wconv_k<<<8, 256, 0, stream>>>(Wb1, wfb1);
    wconv_k<<<8, 256, 0, stream>>>(Wa0, wfa0);
    wconv_k<<<8, 256, 0, stream>>>(Wa1, wfa1);
    wconv_k<<<8, 256, 0, stream>>>(Wa2, wfa2);

    // CSR build (bucketed two-pass; per-node counts/scan/row_ptr/dinv all inside cscat2_k)
    hipMemsetAsync(bcnt, 0, 128 * sizeof(int), stream);
    bhist_k<<<(NE + PTILE - 1) / PTILE, 256, 0, stream>>>(ei, bcnt);
    bkt_scan_k<<<1, 128, 0, stream>>>(bcnt, boff, btail, row_ptr);
    part_k<<<(NE + PTILE - 1) / PTILE, 256, 0, stream>>>(ei, btail, part);
    cscat2_k<<<NBKT, 256, 0, stream>>>(part, boff, row_ptr, dinv, csr_src);

    auto conv = [&](const float* in, const unsigned short* wfrag, const float* b,
                    const float* ss, float* o) {
        gemm_k<<<(NN + 63) / 64, 256, 0, stream>>>(in, wfrag, ss, (unsigned short*)hw16);
        csr_agg_k<<<(NN * 64 + 255) / 256, 256, 0, stream>>>(row_ptr, csr_src, hw16, b, dinv, o);
    };
    auto bn_stats = [&](const float* h, const float* g, const float* beta) {
        hipMemsetAsync(bnss, 0, 256 * sizeof(float), stream);
        bn_stats_k<<<(NN + 127) / 128, 256, 0, stream>>>(h, bnss);
        bn_finalize_k<<<1, 128, 0, stream>>>(bnss, g, beta, ssbuf);
    };

    conv(x, wfb0, bb0, nullptr, bufB);           // conv b0
    bn_stats(bufB, gb0, betab0);
    conv(bufB, wfb1, bb1, ssbuf, bufC);          // conv b1 (A-load: gelu(bn(h)))
    conv(bufC, wfa0, ba0, nullptr, bufB);        // conv a0
    bn_stats(bufB, ga0, bea0);
    conv(bufB, wfa1, ba1, ssbuf, bufC);          // conv a1
    bn_stats(bufC, ga1, bea1);
    conv(bufC, wfa2, ba2, ssbuf, bufB);          // conv a2

    hipMemsetAsync(psum, 0, NG * CH * sizeof(float), stream);
    pool_sum_k<<<(NN + POOL_CHUNK - 1) / POOL_CHUNK, 128, 0, stream>>>(bufB, batch, psum);
    pool_div_k<<<NG, 128, 0, stream>>>(psum, batch, pooled);
    head_k<<<NG, 128, 0, stream>>>(pooled, Wh0, bh0, Wh1, bh1, Wh2, bh2, out);
}

// Round 10
// 592.416 us; speedup vs baseline: 1.1331x; 1.0050x over previous
//
#include <hip/hip_runtime.h>
#include <math.h>

#define NN 50000
#define NE 800000
#define CH 128
#define NG 64
#define BN_EPS 1e-5f
#define POOL_CHUNK 64
#define BKT_SHIFT 9
#define NBKT ((NN + 511) >> 9)              // 98 buckets of 512 nodes
#define PTILE 2048
#define CAP 16384                           // per-bucket edge capacity (expect ~8200)

typedef short bfrag8 __attribute__((ext_vector_type(8)));   // 8 bf16 (4 VGPRs)
typedef float facc4 __attribute__((ext_vector_type(4)));    // 4 fp32 acc

__device__ __forceinline__ float gelu_f(float x) {
    return 0.5f * x * (1.0f + erff(x * 0.70710678118654752440f));
}

// bf16 helpers (RNE pack, bit-exact unpack)
__device__ __forceinline__ unsigned int f2bf(float f) {
    unsigned int u = __float_as_uint(f);
    return (u + 0x7FFFu + ((u >> 16) & 1u)) >> 16;
}
__device__ __forceinline__ unsigned int pack_bf2(float lo, float hi) {
    return (f2bf(hi) << 16) | f2bf(lo);
}
__device__ __forceinline__ float bf_lo(unsigned int v) { return __uint_as_float(v << 16); }
__device__ __forceinline__ float bf_hi(unsigned int v) { return __uint_as_float(v & 0xFFFF0000u); }

// ---------------- pass A: partition edges by dst bucket (capacity-strided) ----------------
__global__ __launch_bounds__(256) void part_k(const int* __restrict__ ei,
                                              int* __restrict__ btail,
                                              unsigned long long* __restrict__ part) {
    __shared__ int lh[NBKT];
    __shared__ int gbase[NBKT];
    int t = threadIdx.x;
    int base = blockIdx.x * PTILE;
    if (t < NBKT) lh[t] = 0;
    __syncthreads();
    int s[8], d[8], rk[8];
    #pragma unroll
    for (int i = 0; i < 8; ++i) {
        int e = base + i * 256 + t;
        if (e < NE) {
            s[i] = ei[e];
            d[i] = ei[NE + e];
            rk[i] = atomicAdd(&lh[d[i] >> BKT_SHIFT], 1);
        }
    }
    __syncthreads();
    if (t < NBKT && lh[t]) gbase[t] = t * CAP + atomicAdd(&btail[t], lh[t]);
    __syncthreads();
    #pragma unroll
    for (int i = 0; i < 8; ++i) {
        int e = base + i * 256 + t;
        if (e < NE) {
            int b = d[i] >> BKT_SHIFT;
            part[gbase[b] + rk[i]] =
                ((unsigned long long)(unsigned int)d[i] << 32) | (unsigned int)s[i];
        }
    }
}

// ---------------- pass B: per-bucket count+scan+emit row_ptr/row_cnt/dinv + scatter ----------------
__global__ __launch_bounds__(256) void cscat2_k(const unsigned long long* __restrict__ part,
                                                const int* __restrict__ btail,
                                                int* __restrict__ row_ptr,
                                                int* __restrict__ row_cnt,
                                                float* __restrict__ dinv,
                                                int* __restrict__ csr_src) {
    __shared__ int cnt_l[512];
    __shared__ int off_l[512];
    __shared__ int psc[256];
    int b = blockIdx.x;
    int n0 = b << BKT_SHIFT;
    int t = threadIdx.x;
    cnt_l[t] = 0;
    cnt_l[t + 256] = 0;
    __syncthreads();
    int e0 = b * CAP, e1 = e0 + btail[b];
    for (int e = e0 + t; e < e1; e += 256) {
        int d = (int)(part[e] >> 32);
        atomicAdd(&cnt_l[d - n0], 1);
    }
    __syncthreads();
    int c0 = cnt_l[2 * t], c1 = cnt_l[2 * t + 1];
    psc[t] = c0 + c1;
    __syncthreads();
    for (int off = 1; off < 256; off <<= 1) {
        int a = (t >= off) ? psc[t - off] : 0;
        __syncthreads();
        psc[t] += a;
        __syncthreads();
    }
    int excl = (t == 0) ? 0 : psc[t - 1];
    off_l[2 * t] = excl;
    off_l[2 * t + 1] = excl + c0;
    #pragma unroll
    for (int k = 0; k < 2; ++k) {
        int ln = 2 * t + k;
        int n = n0 + ln;
        if (n < NN) {
            int c = (k == 0) ? c0 : c1;
            row_ptr[n] = e0 + off_l[ln];
            row_cnt[n] = c;
            dinv[n] = rsqrtf((float)c + 1.0f);   // +1 = self loop
        }
    }
    __syncthreads();
    cnt_l[t] = 0;
    cnt_l[t + 256] = 0;
    __syncthreads();
    for (int e = e0 + t; e < e1; e += 256) {
        unsigned long long p = part[e];
        int s = (int)(unsigned int)p;
        int ld = (int)(p >> 32) - n0;
        int pos = e0 + off_l[ld] + atomicAdd(&cnt_l[ld], 1);
        csr_src[pos] = s;
    }
}

// ---------------- all 5 W -> bf16 B-fragment-order packs in one launch ----------------
__global__ __launch_bounds__(256) void wconv_all_k(const float* __restrict__ W0,
                                                   const float* __restrict__ W1,
                                                   const float* __restrict__ W2,
                                                   const float* __restrict__ W3,
                                                   const float* __restrict__ W4,
                                                   unsigned short* __restrict__ wf) {
    int which = blockIdx.x >> 3;
    int u = (blockIdx.x & 7) * 256 + threadIdx.x;   // 0..2047
    const float* W = (which == 0) ? W0 : (which == 1) ? W1 : (which == 2) ? W2
                   : (which == 3) ? W3 : W4;
    unsigned short* dst_wf = wf + (size_t)which * 16384;
    int nt = u >> 8, kc = (u >> 6) & 3, l = u & 63;
    int kbase = kc * 32 + (l >> 4) * 8;
    int n = nt * 16 + (l & 15);
    unsigned int p[4];
    #pragma unroll
    for (int jj = 0; jj < 4; ++jj) {
        float a = W[(kbase + 2 * jj) * 128 + n];
        float b = W[(kbase + 2 * jj + 1) * 128 + n];
        p[jj] = pack_bf2(a, b);
    }
    *(uint4*)(dst_wf + (size_t)u * 8) = make_uint4(p[0], p[1], p[2], p[3]);
}

// ---------------- MFMA GEMM body (shared by both input variants) ----------------
__device__ __forceinline__ void gemm_core(unsigned short* Alds, unsigned short* Wlds,
                                          const unsigned short* wfrag, int tid,
                                          int row0, unsigned int* out16) {
    #pragma unroll
    for (int i = 0; i < 8; ++i) {
        int linear = tid + i * 256;
        ((uint4*)Wlds)[linear] = ((const uint4*)wfrag)[linear];
    }
    __syncthreads();

    const int w = tid >> 6;
    const int l = tid & 63;
    const int quad = l >> 4;
    const int m = l & 15;

    facc4 acc[8];
    #pragma unroll
    for (int nt = 0; nt < 8; ++nt) acc[nt] = (facc4){0.f, 0.f, 0.f, 0.f};

    #pragma unroll
    for (int kc = 0; kc < 4; ++kc) {
        bfrag8 a = *((const bfrag8*)(Alds + ((size_t)((w * 4 + kc) * 64 + l)) * 8));
        #pragma unroll
        for (int nt = 0; nt < 8; ++nt) {
            bfrag8 b = *((const bfrag8*)(Wlds + ((size_t)((nt * 4 + kc) * 64 + l)) * 8));
            acc[nt] = __builtin_amdgcn_mfma_f32_16x16x32_bf16(a, b, acc[nt], 0, 0, 0);
        }
    }

    // C/D layout: col = nt*16+m, row = w*16 + quad*4 + r
    #pragma unroll
    for (int nt = 0; nt < 8; ++nt) {
        #pragma unroll
        for (int r = 0; r < 4; ++r) {
            int row = row0 + w * 16 + quad * 4 + r;
            if (row < NN)
                ((unsigned short*)out16)[(size_t)row * 128 + nt * 16 + m] =
                    (unsigned short)f2bf(acc[nt][r]);
        }
    }
}

// fp32 input (first conv only, no BN)
__global__ __launch_bounds__(256) void gemm_f32_k(const float* __restrict__ A,
                                                  const unsigned short* __restrict__ wfrag,
                                                  unsigned int* __restrict__ out16) {
    __shared__ unsigned short Alds[8192];
    __shared__ unsigned short Wlds[16384];
    const int tid = threadIdx.x;
    const int row0 = blockIdx.x * 64;
    #pragma unroll
    for (int i = 0; i < 4; ++i) {
        int linear = tid + i * 256;
        int r = linear >> 4;
        int g = linear & 15;
        float4 v0 = make_float4(0.f, 0.f, 0.f, 0.f);
        float4 v1 = make_float4(0.f, 0.f, 0.f, 0.f);
        if (row0 + r < NN) {
            const float4* src = (const float4*)&A[(size_t)(row0 + r) * 128 + g * 8];
            v0 = src[0];
            v1 = src[1];
        }
        int unit = (((r >> 4) * 4 + (g >> 2)) * 64) + ((g & 3) * 16) + (r & 15);
        *(uint4*)(Alds + (size_t)unit * 8) =
            make_uint4(pack_bf2(v0.x, v0.y), pack_bf2(v0.z, v0.w),
                       pack_bf2(v1.x, v1.y), pack_bf2(v1.z, v1.w));
    }
    gemm_core(Alds, Wlds, wfrag, tid, row0, out16);
}

// bf16 input; if ss != null apply gelu(bn(h)) on load
__global__ __launch_bounds__(256) void gemm_bf16_k(const unsigned int* __restrict__ h16,
                                                   const unsigned short* __restrict__ wfrag,
                                                   const float* __restrict__ ss,
                                                   unsigned int* __restrict__ out16) {
    __shared__ unsigned short Alds[8192];
    __shared__ unsigned short Wlds[16384];
    const int tid = threadIdx.x;
    const int row0 = blockIdx.x * 64;
    #pragma unroll
    for (int i = 0; i < 4; ++i) {
        int linear = tid + i * 256;
        int r = linear >> 4;
        int g = linear & 15;
        uint4 v = make_uint4(0u, 0u, 0u, 0u);
        if (row0 + r < NN)
            v = ((const uint4*)h16)[(size_t)(row0 + r) * 16 + g];
        if (ss) {
            float4 sc0 = ((const float4*)ss)[g * 2];
            float4 sh0 = ((const float4*)ss)[32 + g * 2];
            float4 sc1 = ((const float4*)ss)[g * 2 + 1];
            float4 sh1 = ((const float4*)ss)[32 + g * 2 + 1];
            float f0 = gelu_f(bf_lo(v.x) * sc0.x + sh0.x);
            float f1 = gelu_f(bf_hi(v.x) * sc0.y + sh0.y);
            float f2 = gelu_f(bf_lo(v.y) * sc0.z + sh0.z);
            float f3 = gelu_f(bf_hi(v.y) * sc0.w + sh0.w);
            float f4 = gelu_f(bf_lo(v.z) * sc1.x + sh1.x);
            float f5 = gelu_f(bf_hi(v.z) * sc1.y + sh1.y);
            float f6 = gelu_f(bf_lo(v.w) * sc1.z + sh1.z);
            float f7 = gelu_f(bf_hi(v.w) * sc1.w + sh1.w);
            v = make_uint4(pack_bf2(f0, f1), pack_bf2(f2, f3),
                           pack_bf2(f4, f5), pack_bf2(f6, f7));
        }
        int unit = (((r >> 4) * 4 + (g >> 2)) * 64) + ((g & 3) * 16) + (r & 15);
        *(uint4*)(Alds + (size_t)unit * 8) = v;
    }
    gemm_core(Alds, Wlds, wfrag, tid, row0, out16);
}

// ---------------- CSR aggregation: one wave per node, bf16 gather, bf16 out ----------------
__global__ __launch_bounds__(256) void csr_agg_k(const int* __restrict__ row_ptr,
                                                 const int* __restrict__ row_cnt,
                                                 const int* __restrict__ csr_src,
                                                 const unsigned int* __restrict__ hw16,
                                                 const float* __restrict__ bias,
                                                 const float* __restrict__ dinv,
                                                 unsigned int* __restrict__ out16) {
    int node = (blockIdx.x * 256 + threadIdx.x) >> 6;
    if (node >= NN) return;
    int lane = threadIdx.x & 63;

    float di = dinv[node];
    float sw = di * di;
    float2 b = ((const float2*)bias)[lane];
    unsigned int hs = hw16[(size_t)node * 64 + lane];
    float selfx = b.x + bf_lo(hs) * sw;
    float selfy = b.y + bf_hi(hs) * sw;

    float a0x = 0.f, a0y = 0.f, a1x = 0.f, a1y = 0.f;
    float a2x = 0.f, a2y = 0.f, a3x = 0.f, a3y = 0.f;

    int j = row_ptr[node];
    int j1 = j + row_cnt[node];
    for (; j + 7 < j1; j += 8) {
        int s[8];
        #pragma unroll
        for (int k = 0; k < 8; ++k) s[k] = csr_src[j + k];
        float w[8];
        #pragma unroll
        for (int k = 0; k < 8; ++k) w[k] = dinv[s[k]];
        unsigned int v[8];
        #pragma unroll
        for (int k = 0; k < 8; ++k) v[k] = hw16[(size_t)s[k] * 64 + lane];
        a0x += bf_lo(v[0]) * w[0] + bf_lo(v[1]) * w[1];
        a0y += bf_hi(v[0]) * w[0] + bf_hi(v[1]) * w[1];
        a1x += bf_lo(v[2]) * w[2] + bf_lo(v[3]) * w[3];
        a1y += bf_hi(v[2]) * w[2] + bf_hi(v[3]) * w[3];
        a2x += bf_lo(v[4]) * w[4] + bf_lo(v[5]) * w[5];
        a2y += bf_hi(v[4]) * w[4] + bf_hi(v[5]) * w[5];
        a3x += bf_lo(v[6]) * w[6] + bf_lo(v[7]) * w[7];
        a3y += bf_hi(v[6]) * w[6] + bf_hi(v[7]) * w[7];
    }
    for (; j + 1 < j1; j += 2) {
        int s0 = csr_src[j], s1 = csr_src[j + 1];
        float w0 = dinv[s0], w1 = dinv[s1];
        unsigned int v0 = hw16[(size_t)s0 * 64 + lane];
        unsigned int v1 = hw16[(size_t)s1 * 64 + lane];
        a0x += bf_lo(v0) * w0 + bf_lo(v1) * w1;
        a0y += bf_hi(v0) * w0 + bf_hi(v1) * w1;
    }
    if (j < j1) {
        int s = csr_src[j];
        float w = dinv[s];
        unsigned int v = hw16[(size_t)s * 64 + lane];
        a0x += bf_lo(v) * w;
        a0y += bf_hi(v) * w;
    }
    float ox = selfx + di * ((a0x + a1x) + (a2x + a3x));
    float oy = selfy + di * ((a0y + a1y) + (a2y + a3y));
    out16[(size_t)node * 64 + lane] = pack_bf2(ox, oy);
}

// ---------------- batchnorm stats over bf16 h, fused last-block finalize ----------------
__global__ __launch_bounds__(256) void bn_stats_k(const unsigned int* __restrict__ h16,
                                                  float* __restrict__ sums,
                                                  int* __restrict__ counter,
                                                  const float* __restrict__ g,
                                                  const float* __restrict__ beta,
                                                  float* __restrict__ ssout) {
    int t = threadIdx.x;
    int cp = t & 63;         // uint column (2 channels)
    int quad = t >> 6;       // 4 row strips
    float s0 = 0.f, q0 = 0.f, s1 = 0.f, q1 = 0.f;
    int r0 = blockIdx.x * 128 + quad;
    #pragma unroll 4
    for (int i = 0; i < 32; ++i) {
        int r = r0 + i * 4;
        if (r < NN) {
            unsigned int v = h16[(size_t)r * 64 + cp];
            float f0 = bf_lo(v), f1 = bf_hi(v);
            s0 += f0; q0 += f0 * f0;
            s1 += f1; q1 += f1 * f1;
        }
    }
    __shared__ float A0[256], A1[256], A2[256], A3[256];
    A0[t] = s0; A1[t] = q0; A2[t] = s1; A3[t] = q1;
    __syncthreads();
    if (t < 64) {
        float ts0 = A0[t] + A0[64 + t] + A0[128 + t] + A0[192 + t];
        float tq0 = A1[t] + A1[64 + t] + A1[128 + t] + A1[192 + t];
        float ts1 = A2[t] + A2[64 + t] + A2[128 + t] + A2[192 + t];
        float tq1 = A3[t] + A3[64 + t] + A3[128 + t] + A3[192 + t];
        atomicAdd(&sums[2 * t], ts0);
        atomicAdd(&sums[2 * t + 1], ts1);
        atomicAdd(&sums[128 + 2 * t], tq0);
        atomicAdd(&sums[129 + 2 * t], tq1);
    }
    __threadfence();
    __syncthreads();
    __shared__ int isLast;
    if (t == 0) isLast = (atomicAdd(counter, 1) == (int)gridDim.x - 1);
    __syncthreads();
    if (isLast) {
        if (t < 128) {
            float sv = atomicAdd(&sums[t], 0.f);          // L2-coherent read
            float qv = atomicAdd(&sums[128 + t], 0.f);
            float mean = sv * (1.0f / NN);
            float var = qv * (1.0f / NN) - mean * mean;
            float sc = g[t] * rsqrtf(var + BN_EPS);
            ssout[t] = sc;
            ssout[128 + t] = beta[t] - mean * sc;
            sums[t] = 0.f;                                 // reset for next use
            sums[128 + t] = 0.f;
        }
        if (t == 0) *counter = 0;
    }
}

// ---------------- global mean pool sum (bf16 input) ----------------
__global__ __launch_bounds__(128) void pool_sum_k(const unsigned int* __restrict__ h16,
                                                  const int* __restrict__ batch,
                                                  float* __restrict__ sums) {
    int r0 = blockIdx.x * POOL_CHUNK;
    int r1 = min(r0 + POOL_CHUNK, NN);
    if (r0 >= NN) return;
    int c = threadIdx.x;
    int cp = c >> 1, hi = c & 1;
    float acc = 0.f;
    int g = batch[r0];
    for (int r = r0; r < r1; ++r) {
        int gr = batch[r];
        if (gr != g) {
            atomicAdd(&sums[g * 128 + c], acc);
            acc = 0.f;
            g = gr;
        }
        unsigned int v = h16[(size_t)r * 64 + cp];
        acc += hi ? bf_hi(v) : bf_lo(v);
    }
    atomicAdd(&sums[g * 128 + c], acc);
}

__device__ __forceinline__ int lower_bound_dev(const int* __restrict__ a, int n, int key) {
    int lo = 0, hi = n;
    while (lo < hi) {
        int mid = (lo + hi) >> 1;
        if (a[mid] < key) lo = mid + 1; else hi = mid;
    }
    return lo;
}

// ---------------- MLP head (pool-div fused) ----------------
__global__ __launch_bounds__(128) void head_k(const float* __restrict__ psum,
                                              const int* __restrict__ batch,
                                              const float* __restrict__ W0, const float* __restrict__ b0,
                                              const float* __restrict__ W1, const float* __restrict__ b1,
                                              const float* __restrict__ W2, const float* __restrict__ b2,
                                              float* __restrict__ out) {
    __shared__ float r0[128], r1[128];
    int g = blockIdx.x, t = threadIdx.x;
    int a = lower_bound_dev(batch, NN, g);
    int b = lower_bound_dev(batch, NN, g + 1);
    float inv = 1.0f / fmaxf((float)(b - a), 1.0f);
    r0[t] = psum[g * 128 + t] * inv;
    __syncthreads();
    float acc = b0[t];
    for (int k = 0; k < 128; ++k) acc += r0[k] * W0[k * 128 + t];
    r1[t] = gelu_f(acc);
    __syncthreads();
    acc = b1[t];
    for (int k = 0; k < 128; ++k) acc += r1[k] * W1[k * 128 + t];
    float y = gelu_f(acc);
    __syncthreads();
    r0[t] = y;
    __syncthreads();
    if (t < 10) {
        acc = b2[t];
        for (int k = 0; k < 128; ++k) acc += r0[k] * W2[k * 10 + t];
        out[g * 10 + t] = acc;
    }
}

extern "C" void kernel_launch(void* const* d_in, const int* in_sizes, int n_in,
                              void* d_out, int out_size, void* d_ws, size_t ws_size,
                              hipStream_t stream) {
    const float* x      = (const float*)d_in[0];
    const int*   ei     = (const int*)d_in[1];
    const int*   batch  = (const int*)d_in[2];
    const float* Wb0    = (const float*)d_in[4];
    const float* bb0    = (const float*)d_in[5];
    const float* gb0    = (const float*)d_in[6];
    const float* betab0 = (const float*)d_in[7];
    const float* Wb1    = (const float*)d_in[8];
    const float* bb1    = (const float*)d_in[9];
    const float* Wa0    = (const float*)d_in[10];
    const float* ba0    = (const float*)d_in[11];
    const float* ga0    = (const float*)d_in[12];
    const float* bea0   = (const float*)d_in[13];
    const float* Wa1    = (const float*)d_in[14];
    const float* ba1    = (const float*)d_in[15];
    const float* ga1    = (const float*)d_in[16];
    const float* bea1   = (const float*)d_in[17];
    const float* Wa2    = (const float*)d_in[18];
    const float* ba2    = (const float*)d_in[19];
    const float* Wh0    = (const float*)d_in[20];
    const float* bh0    = (const float*)d_in[21];
    const float* Wh1    = (const float*)d_in[22];
    const float* bh1    = (const float*)d_in[23];
    const float* Wh2    = (const float*)d_in[24];
    const float* bh2    = (const float*)d_in[25];
    float* out = (float*)d_out;

    char* ws = (char*)d_ws;
    unsigned int* hw16 = (unsigned int*)ws;             ws += (size_t)NN * 64 * 4;   // GEMM out (bf16x2)
    unsigned int* hB   = (unsigned int*)ws;             ws += (size_t)NN * 64 * 4;   // conv out (bf16x2)
    unsigned int* hC   = (unsigned int*)ws;             ws += (size_t)NN * 64 * 4;
    float* dinv    = (float*)ws;                        ws += (size_t)NN * 4;
    int*   row_ptr = (int*)ws;                          ws += (size_t)(NN + 4) * 4;
    int*   row_cnt = (int*)ws;                          ws += (size_t)NN * 4;
    int*   csr_src = (int*)ws;                          ws += (size_t)NBKT * CAP * 4;  // strided index space!
    unsigned long long* part = (unsigned long long*)ws; ws += (size_t)NBKT * CAP * 8;
    unsigned short* wf = (unsigned short*)ws;           ws += (size_t)5 * 16384 * 2;
    float* ssbuf   = (float*)ws;                        ws += 256 * 4;
    // ---- zero region (single memset) ----
    char* zbase = ws;
    int*   btail   = (int*)ws;                          ws += 128 * 4;
    float* bnsums  = (float*)ws;                        ws += 256 * 4;
    int*   bncnt   = (int*)ws;                          ws += 4 * 4;
    float* psum    = (float*)ws;                        ws += (size_t)NG * CH * 4;
    size_t zbytes = (size_t)(ws - zbase);

    unsigned short* wfb0 = wf;
    unsigned short* wfb1 = wf + 16384;
    unsigned short* wfa0 = wf + 2 * 16384;
    unsigned short* wfa1 = wf + 3 * 16384;
    unsigned short* wfa2 = wf + 4 * 16384;

    hipMemsetAsync(zbase, 0, zbytes, stream);
    wconv_all_k<<<40, 256, 0, stream>>>(Wb0, Wb1, Wa0, Wa1, Wa2, wf);

    // CSR build: capacity-strided buckets, no global scans
    part_k<<<(NE + PTILE - 1) / PTILE, 256, 0, stream>>>(ei, btail, part);
    cscat2_k<<<NBKT, 256, 0, stream>>>(part, btail, row_ptr, row_cnt, dinv, csr_src);

    auto agg = [&](const float* b, unsigned int* o) {
        csr_agg_k<<<(NN * 64 + 255) / 256, 256, 0, stream>>>(row_ptr, row_cnt, csr_src,
                                                             hw16, b, dinv, o);
    };
    auto bn_stats = [&](const unsigned int* h, const float* g, const float* beta) {
        bn_stats_k<<<(NN + 127) / 128, 256, 0, stream>>>(h, bnsums, bncnt, g, beta, ssbuf);
    };

    // conv b0 (fp32 input x)
    gemm_f32_k<<<(NN + 63) / 64, 256, 0, stream>>>(x, wfb0, hw16);
    agg(bb0, hB);
    bn_stats(hB, gb0, betab0);
    // conv b1 (BN+GELU fused on load)
    gemm_bf16_k<<<(NN + 63) / 64, 256, 0, stream>>>(hB, wfb1, ssbuf, hw16);
    agg(bb1, hC);
    // conv a0 (no BN)
    gemm_bf16_k<<<(NN + 63) / 64, 256, 0, stream>>>(hC, wfa0, nullptr, hw16);
    agg(ba0, hB);
    bn_stats(hB, ga0, bea0);
    // conv a1
    gemm_bf16_k<<<(NN + 63) / 64, 256, 0, stream>>>(hB, wfa1, ssbuf, hw16);
    agg(ba1, hC);
    bn_stats(hC, ga1, bea1);
    // conv a2
    gemm_bf16_k<<<(NN + 63) / 64, 256, 0, stream>>>(hC, wfa2, ssbuf, hw16);
    agg(ba2, hB);

    pool_sum_k<<<(NN + POOL_CHUNK - 1) / POOL_CHUNK, 128, 0, stream>>>(hB, batch, psum);
    head_k<<<NG, 128, 0, stream>>>(psum, batch, Wh0, bh0, Wh1, bh1, Wh2, bh2, out);
}